// Round 1
// baseline (503.859 us; speedup 1.0000x reference)
//
#include <hip/hip_runtime.h>

#define BLK 256
#define LOWN 8192     // 2^13 contiguous span per pass-A block
#define ROWS 512      // 2^9 high-index rows for pass B
#define HSTAGES 9
#define NORM11 0x1p-11f   // 1/sqrt(2^22), exact

// XOR swizzle for pass-A LDS: spreads bits 5-7 into bank-group bits 2-4.
// Involution; preserves float4 (16B) alignment since it only flips bits 2-4.
__device__ __forceinline__ int swz(int f) { return f ^ (((f >> 5) & 7) << 2); }

// ---------------- pass A: FWHT over low 13 bits (contiguous 8192/block) -------------
// V=0: pre = B[g] * sum_t w[t]*tv[t][g]                 (K1)
// V=1: pre = src[Pi[g]] * G[g]                          (K3)
// V=2: pre = plain load; post = *2^-11 * G[g]           (K5)
// V=3: pre = src[invPi[g]]                              (K6)
template<int V>
__global__ __launch_bounds__(BLK) void passA(
    const float* src, float* dst,
    const float* __restrict__ aux, const int* __restrict__ idx,
    const float* __restrict__ w8, long D)
{
  __shared__ float lds[LOWN];
  const int t = threadIdx.x;
  const long base = (long)blockIdx.x * LOWN;

  float wreg[8];
  if constexpr (V == 0) {
    #pragma unroll
    for (int i = 0; i < 8; i++) wreg[i] = w8[i];
  }

  // ---- load (coalesced float4) with fused pre-op ----
  #pragma unroll
  for (int k = 0; k < 8; k++) {
    const int p = k*BLK + t;          // float4 index within block
    const long g = base + (long)p*4;  // global float index
    float4 v;
    if constexpr (V == 0) {
      float ax = 0.f, ay = 0.f, az = 0.f, aw = 0.f;
      #pragma unroll
      for (int tt = 0; tt < 8; tt++) {
        const float4 x = *(const float4*)(src + (long)tt*D + g);
        ax = fmaf(wreg[tt], x.x, ax);
        ay = fmaf(wreg[tt], x.y, ay);
        az = fmaf(wreg[tt], x.z, az);
        aw = fmaf(wreg[tt], x.w, aw);
      }
      const float4 b4 = *(const float4*)(aux + g);
      v.x = ax*b4.x; v.y = ay*b4.y; v.z = az*b4.z; v.w = aw*b4.w;
    } else if constexpr (V == 1) {
      const int4  p4 = *(const int4*)(idx + g);
      const float4 g4 = *(const float4*)(aux + g);
      v.x = src[p4.x]*g4.x; v.y = src[p4.y]*g4.y;
      v.z = src[p4.z]*g4.z; v.w = src[p4.w]*g4.w;
    } else if constexpr (V == 2) {
      v = *(const float4*)(src + g);
    } else {
      const int4 p4 = *(const int4*)(idx + g);
      v.x = src[p4.x]; v.y = src[p4.y]; v.z = src[p4.z]; v.w = src[p4.w];
    }
    *(float4*)(lds + swz(p*4)) = v;
  }
  __syncthreads();

  // ---- 5 register stages (h=1..16) on 32 consecutive elements per thread ----
  float r[32];
  #pragma unroll
  for (int j = 0; j < 8; j++) {
    const float4 v = *(const float4*)(lds + swz(t*32 + j*4));
    r[4*j+0]=v.x; r[4*j+1]=v.y; r[4*j+2]=v.z; r[4*j+3]=v.w;
  }
  #pragma unroll
  for (int s = 0; s < 5; s++) {
    const int h = 1 << s;
    #pragma unroll
    for (int b = 0; b < 16; b++) {
      const int i = ((b >> s) << (s+1)) | (b & (h-1));
      const float u = r[i], w = r[i+h];
      r[i] = u + w; r[i+h] = u - w;
    }
  }
  #pragma unroll
  for (int j = 0; j < 8; j++) {
    float4 v; v.x=r[4*j+0]; v.y=r[4*j+1]; v.z=r[4*j+2]; v.w=r[4*j+3];
    *(float4*)(lds + swz(t*32 + j*4)) = v;
  }
  __syncthreads();

  // ---- 8 LDS stages (h=32..4096); i low5 = lane low5 -> ~2-way banks ----
  for (int s = 5; s < 13; s++) {
    const int h = 1 << s;
    #pragma unroll
    for (int k = 0; k < 16; k++) {
      const int b = t + BLK*k;
      const int i = ((b >> s) << (s+1)) | (b & (h-1));
      const int f1 = swz(i), f2 = swz(i+h);
      const float u = lds[f1], w = lds[f2];
      lds[f1] = u + w; lds[f2] = u - w;
    }
    __syncthreads();
  }

  // ---- store (coalesced float4) with fused post-op ----
  #pragma unroll
  for (int k = 0; k < 8; k++) {
    const int p = k*BLK + t;
    const long g = base + (long)p*4;
    float4 v = *(const float4*)(lds + swz(p*4));
    if constexpr (V == 2) {
      const float4 g4 = *(const float4*)(aux + g);
      v.x *= NORM11*g4.x; v.y *= NORM11*g4.y;
      v.z *= NORM11*g4.z; v.w *= NORM11*g4.w;
    }
    *(float4*)(dst + g) = v;
  }
}

// ---------------- pass B: FWHT over high 9 bits (512 rows x 16 cols tile) -----------
__device__ __forceinline__ void fwht_rows(float* lds, int t)
{
  #pragma unroll
  for (int s = 0; s < HSTAGES; s++) {
    const int h = 1 << s;
    #pragma unroll
    for (int k = 0; k < 16; k++) {
      const int q = t + BLK*k;                 // 4096 butterflies/stage
      const int col = q & 15, b = q >> 4;
      const int i = ((b >> s) << (s+1)) | (b & (h-1));
      const int f1 = (i << 4) + col, f2 = f1 + (h << 4);
      const float u = lds[f1], w = lds[f2];
      lds[f1] = u + w; lds[f2] = u - w;
    }
    __syncthreads();
  }
}

// V=0: post *2^-11                                  (K2, in-place)
// V=1: 9 stages; *2^-11*mask; 9 more stages         (K4, in-place, fuses FWHT2hi+mask+FWHT3hi)
// V=2: post: out = v*2^-11*B + pretrained           (K7)
template<int V>
__global__ __launch_bounds__(BLK) void passB(
    const float* src, float* dst,
    const unsigned char* __restrict__ mask,
    const float* __restrict__ bvec, const float* __restrict__ pvec, long D)
{
  __shared__ float lds[ROWS*16];
  const int t = threadIdx.x;
  const long J0 = (long)blockIdx.x * 16;

  #pragma unroll
  for (int k = 0; k < 32; k++) {
    const int e = t + BLK*k;
    const int row = e >> 4, col = e & 15;
    lds[e] = src[(long)row*LOWN + J0 + col];
  }
  __syncthreads();

  fwht_rows(lds, t);

  if constexpr (V == 1) {
    #pragma unroll
    for (int k = 0; k < 32; k++) {
      const int e = t + BLK*k;
      const int row = e >> 4, col = e & 15;
      const long g = (long)row*LOWN + J0 + col;
      lds[e] *= NORM11 * (float)mask[g];
    }
    __syncthreads();
    fwht_rows(lds, t);
  }

  #pragma unroll
  for (int k = 0; k < 32; k++) {
    const int e = t + BLK*k;
    const int row = e >> 4, col = e & 15;
    const long g = (long)row*LOWN + J0 + col;
    float v = lds[e];
    if constexpr (V == 0) v *= NORM11;
    if constexpr (V == 2) v = fmaf(v*NORM11, bvec[g], pvec[g]);
    dst[g] = v;
  }
}

__global__ void scatter_mask(const int* __restrict__ rowIdx,
                             unsigned char* __restrict__ mask, int m)
{
  const int i = blockIdx.x*blockDim.x + threadIdx.x;
  if (i < m) mask[rowIdx[i]] = 1;   // row_idx entries are distinct
}

extern "C" void kernel_launch(void* const* d_in, const int* in_sizes, int n_in,
                              void* d_out, int out_size, void* d_ws, size_t ws_size,
                              hipStream_t stream)
{
  (void)n_in; (void)out_size;
  const float* tv    = (const float*)d_in[0];  // (T, D)
  const float* w     = (const float*)d_in[1];  // (T,)
  const float* prew  = (const float*)d_in[2];  // pretrained (D,)
  const float* B     = (const float*)d_in[3];
  const float* G     = (const float*)d_in[4];
  const int*   Pi    = (const int*)d_in[5];
  const int*   invPi = (const int*)d_in[6];
  const int*   rowIx = (const int*)d_in[7];
  const long D = (long)in_sizes[2];            // 2^22
  const int  m = in_sizes[7];
  float* out = (float*)d_out;

  // Scratch: one D-float ping buffer + D-byte mask. Fallback: reuse task_vectors
  // memory (fully consumed by K1 before any overwrite; harness restores inputs
  // before every launch).
  float* bufA; unsigned char* mask;
  const size_t need = (size_t)D*sizeof(float) + (size_t)D;
  if (ws_size >= need) {
    bufA = (float*)d_ws;
    mask = (unsigned char*)d_ws + (size_t)D*sizeof(float);
  } else {
    bufA = (float*)d_in[0];
    mask = (unsigned char*)((float*)d_in[0] + D);
  }

  const int gA = (int)(D / LOWN);  // 512
  const int gB = LOWN / 16;        // 512

  // K1: combined = sum_t w_t*tv_t, *B, FWHT1-low  -> bufA
  passA<0><<<gA, BLK, 0, stream>>>(tv, bufA, B, nullptr, w, D);
  // mask build (after K1 so the tv-fallback region is free)
  hipMemsetAsync(mask, 0, (size_t)D, stream);
  scatter_mask<<<(m + BLK - 1)/BLK, BLK, 0, stream>>>(rowIx, mask, m);
  // K2: FWHT1-high, *2^-11                         (bufA in-place)
  passB<0><<<gB, BLK, 0, stream>>>(bufA, bufA, nullptr, nullptr, nullptr, D);
  // K3: gather Pi, *G, FWHT2-low                   bufA -> out
  passA<1><<<gA, BLK, 0, stream>>>(bufA, out, G, Pi, nullptr, D);
  // K4: FWHT2-high, *2^-11, *mask, FWHT3-high      (out in-place)
  passB<1><<<gB, BLK, 0, stream>>>(out, out, mask, nullptr, nullptr, D);
  // K5: FWHT3-low, *2^-11, *G                      (out in-place)
  passA<2><<<gA, BLK, 0, stream>>>(out, out, G, nullptr, nullptr, D);
  // K6: gather inv_Pi, FWHT4-low                   out -> bufA
  passA<3><<<gA, BLK, 0, stream>>>(out, bufA, nullptr, invPi, nullptr, D);
  // K7: FWHT4-high, *2^-11*B + pretrained          bufA -> out
  passB<2><<<gB, BLK, 0, stream>>>(bufA, out, nullptr, B, prew, D);
}

// Round 2
// 463.850 us; speedup vs baseline: 1.0863x; 1.0863x over previous
//
#include <hip/hip_runtime.h>

#define NORM11 0x1p-11f   // 1/sqrt(2^22), exact

// XOR swizzle for pass-A LDS: bits 5-7 -> bank bits 2-4. Involution,
// preserves float4 alignment (only flips bits 2-4).
__device__ __forceinline__ int swz(int f) { return f ^ (((f >> 5) & 7) << 2); }

// radix-4 butterfly = two FWHT stages on (a,b,c,d) spaced h, 2h
__device__ __forceinline__ void bf4(float& a, float& b, float& c, float& d) {
  const float ab = a + b, amb = a - b, cd = c + d, cmd = c - d;
  a = ab + cd; b = amb + cmd; c = ab - cd; d = amb - cmd;
}

// ---------------- pass A: FWHT over low 13 bits (contiguous 8192/block) -------------
// V=0: pre = B[g] * sum_t w[t]*tv[t][g]                 (K1)
// V=1: pre = src[Pi[g]] * G[g]                          (K3)
// V=2: pre = plain load; post = *2^-11 * G[g]           (K5)
// V=3: pre = src[invPi[g]]                              (K6)
template<int V>
__global__ __launch_bounds__(512) void passA(
    const float* __restrict__ src, float* __restrict__ dst,
    const float* __restrict__ aux, const int* __restrict__ idx,
    const float* __restrict__ w8, long D)
{
  __shared__ float lds[8192];
  const int t = threadIdx.x;
  const long base = (long)blockIdx.x * 8192;

  // ---- load 4 coalesced float4 (float index 2048k + 4t) with fused pre-op ----
  float r[16];
  #pragma unroll
  for (int k = 0; k < 4; k++) {
    const long g = base + 2048*k + 4*t;
    float4 v;
    if constexpr (V == 0) {
      float ax = 0.f, ay = 0.f, az = 0.f, aw = 0.f;
      #pragma unroll
      for (int tt = 0; tt < 8; tt++) {
        const float4 x = *(const float4*)(src + (long)tt*D + g);
        const float wv = w8[tt];
        ax = fmaf(wv, x.x, ax); ay = fmaf(wv, x.y, ay);
        az = fmaf(wv, x.z, az); aw = fmaf(wv, x.w, aw);
      }
      const float4 b4 = *(const float4*)(aux + g);
      v.x = ax*b4.x; v.y = ay*b4.y; v.z = az*b4.z; v.w = aw*b4.w;
    } else if constexpr (V == 1) {
      const int4  p4 = *(const int4*)(idx + g);
      const float4 g4 = *(const float4*)(aux + g);
      v.x = src[p4.x]*g4.x; v.y = src[p4.y]*g4.y;
      v.z = src[p4.z]*g4.z; v.w = src[p4.w]*g4.w;
    } else if constexpr (V == 2) {
      v = *(const float4*)(src + g);
    } else {
      const int4 p4 = *(const int4*)(idx + g);
      v.x = src[p4.x]; v.y = src[p4.y]; v.z = src[p4.z]; v.w = src[p4.w];
    }
    r[4*k+0] = v.x; r[4*k+1] = v.y; r[4*k+2] = v.z; r[4*k+3] = v.w;
  }

  // ---- register stages: h=1,2 (within float4) and h=2048,4096 (across k) ----
  #pragma unroll
  for (int k = 0; k < 4; k++) bf4(r[4*k+0], r[4*k+1], r[4*k+2], r[4*k+3]);
  #pragma unroll
  for (int j = 0; j < 4; j++) bf4(r[j], r[4+j], r[8+j], r[12+j]);

  // ---- spill to LDS (swizzled) ----
  #pragma unroll
  for (int k = 0; k < 4; k++) {
    float4 v; v.x=r[4*k+0]; v.y=r[4*k+1]; v.z=r[4*k+2]; v.w=r[4*k+3];
    *(float4*)(lds + swz(2048*k + 4*t)) = v;
  }
  __syncthreads();

  // ---- LDS stages h=4..1024: 4 radix-4 pairs + 1 single ----
  #pragma unroll
  for (int sp = 0; sp < 4; sp++) {
    const int s = 2 + 2*sp;
    const int h = 1 << s;
    #pragma unroll
    for (int k = 0; k < 4; k++) {
      const int q = t + 512*k;                       // 2048 quads
      const int i = ((q >> s) << (s+2)) | (q & (h-1));
      const int f0 = swz(i), f1 = swz(i+h), f2 = swz(i+2*h), f3 = swz(i+3*h);
      float a = lds[f0], b = lds[f1], c = lds[f2], d = lds[f3];
      bf4(a, b, c, d);
      lds[f0] = a; lds[f1] = b; lds[f2] = c; lds[f3] = d;
    }
    __syncthreads();
  }
  {
    const int h = 1024;
    #pragma unroll
    for (int k = 0; k < 8; k++) {
      const int q = t + 512*k;                       // 4096 butterflies
      const int i = ((q >> 10) << 11) | (q & (h-1));
      const int f0 = swz(i), f1 = swz(i + h);
      const float u = lds[f0], w = lds[f1];
      lds[f0] = u + w; lds[f1] = u - w;
    }
    __syncthreads();
  }

  // ---- coalesced float4 store with fused post-op ----
  #pragma unroll
  for (int k = 0; k < 4; k++) {
    const long g = base + 2048*k + 4*t;
    float4 v = *(const float4*)(lds + swz(2048*k + 4*t));
    if constexpr (V == 2) {
      const float4 g4 = *(const float4*)(aux + g);
      v.x *= NORM11*g4.x; v.y *= NORM11*g4.y;
      v.z *= NORM11*g4.z; v.w *= NORM11*g4.w;
    }
    *(float4*)(dst + g) = v;
  }
}

// ---------------- pass B: FWHT over high 9 bits (512 rows x 16 cols tile) -----------
#define BSTRIDE 17   // LDS row stride, coprime with 32 -> bank spread

__device__ __forceinline__ void fwht512rows(float* lds, int t)
{
  // stages h=1..128 as 4 radix-4 pairs
  #pragma unroll
  for (int sp = 0; sp < 4; sp++) {
    const int s = 2*sp;
    const int h = 1 << s;
    #pragma unroll
    for (int k = 0; k < 4; k++) {
      const int q  = t + 512*k;                      // 2048 quads
      const int col = q & 15, qr = q >> 4;           // 128 row-quads
      const int i = ((qr >> s) << (s+2)) | (qr & (h-1));
      const int f0 = i*BSTRIDE + col, f1 = (i+h)*BSTRIDE + col;
      const int f2 = (i+2*h)*BSTRIDE + col, f3 = (i+3*h)*BSTRIDE + col;
      float a = lds[f0], b = lds[f1], c = lds[f2], d = lds[f3];
      bf4(a, b, c, d);
      lds[f0] = a; lds[f1] = b; lds[f2] = c; lds[f3] = d;
    }
    __syncthreads();
  }
  // single stage h=256
  #pragma unroll
  for (int k = 0; k < 8; k++) {
    const int q = t + 512*k;                         // 4096 butterflies
    const int col = q & 15, i = q >> 4;              // i in 0..255
    const int f0 = i*BSTRIDE + col, f1 = (i+256)*BSTRIDE + col;
    const float u = lds[f0], w = lds[f1];
    lds[f0] = u + w; lds[f1] = u - w;
  }
  __syncthreads();
}

// V=0: post *2^-11                                  (K2, in-place)
// V=1: 9 stages; *2^-11*mask; 9 more stages         (K4, in-place)
// V=2: post: out = v*2^-11*B + pretrained           (K7)
template<int V>
__global__ __launch_bounds__(512) void passB(
    const float* __restrict__ src, float* __restrict__ dst,
    const unsigned char* __restrict__ mask,
    const float* __restrict__ bvec, const float* __restrict__ pvec)
{
  __shared__ float lds[512*BSTRIDE];
  const int t = threadIdx.x;
  const long J0 = (long)blockIdx.x * 16;

  // load: float4 per thread-iter; wave covers 16 rows x 64B segments
  #pragma unroll
  for (int k = 0; k < 4; k++) {
    const int e4 = t + 512*k;                        // 2048 float4
    const int row = e4 >> 2, c = (e4 & 3)*4;
    const float4 v = *(const float4*)(src + (long)row*8192 + J0 + c);
    const int ba = row*BSTRIDE + c;
    lds[ba] = v.x; lds[ba+1] = v.y; lds[ba+2] = v.z; lds[ba+3] = v.w;
  }
  __syncthreads();

  fwht512rows(lds, t);

  if constexpr (V == 1) {
    #pragma unroll
    for (int k = 0; k < 4; k++) {
      const int e4 = t + 512*k;
      const int row = e4 >> 2, c = (e4 & 3)*4;
      const long g = (long)row*8192 + J0 + c;
      const uchar4 m4 = *(const uchar4*)(mask + g);
      const int ba = row*BSTRIDE + c;
      lds[ba+0] *= NORM11 * (float)m4.x;
      lds[ba+1] *= NORM11 * (float)m4.y;
      lds[ba+2] *= NORM11 * (float)m4.z;
      lds[ba+3] *= NORM11 * (float)m4.w;
    }
    __syncthreads();
    fwht512rows(lds, t);
  }

  // store with fused post-op
  #pragma unroll
  for (int k = 0; k < 4; k++) {
    const int e4 = t + 512*k;
    const int row = e4 >> 2, c = (e4 & 3)*4;
    const long g = (long)row*8192 + J0 + c;
    const int ba = row*BSTRIDE + c;
    float4 v; v.x = lds[ba]; v.y = lds[ba+1]; v.z = lds[ba+2]; v.w = lds[ba+3];
    if constexpr (V == 0) { v.x*=NORM11; v.y*=NORM11; v.z*=NORM11; v.w*=NORM11; }
    if constexpr (V == 2) {
      const float4 b4 = *(const float4*)(bvec + g);
      const float4 p4 = *(const float4*)(pvec + g);
      v.x = fmaf(v.x*NORM11, b4.x, p4.x); v.y = fmaf(v.y*NORM11, b4.y, p4.y);
      v.z = fmaf(v.z*NORM11, b4.z, p4.z); v.w = fmaf(v.w*NORM11, b4.w, p4.w);
    }
    *(float4*)(dst + g) = v;
  }
}

__global__ void scatter_mask(const int* __restrict__ rowIdx,
                             unsigned char* __restrict__ mask, int m)
{
  const int i = blockIdx.x*blockDim.x + threadIdx.x;
  if (i < m) mask[rowIdx[i]] = 1;   // row_idx entries are distinct
}

extern "C" void kernel_launch(void* const* d_in, const int* in_sizes, int n_in,
                              void* d_out, int out_size, void* d_ws, size_t ws_size,
                              hipStream_t stream)
{
  (void)n_in; (void)out_size;
  const float* tv    = (const float*)d_in[0];  // (T, D)
  const float* w     = (const float*)d_in[1];  // (T,)
  const float* prew  = (const float*)d_in[2];  // pretrained (D,)
  const float* B     = (const float*)d_in[3];
  const float* G     = (const float*)d_in[4];
  const int*   Pi    = (const int*)d_in[5];
  const int*   invPi = (const int*)d_in[6];
  const int*   rowIx = (const int*)d_in[7];
  const long D = (long)in_sizes[2];            // 2^22
  const int  m = in_sizes[7];
  float* out = (float*)d_out;

  float* bufA; unsigned char* mask;
  const size_t need = (size_t)D*sizeof(float) + (size_t)D;
  if (ws_size >= need) {
    bufA = (float*)d_ws;
    mask = (unsigned char*)d_ws + (size_t)D*sizeof(float);
  } else {
    bufA = (float*)d_in[0];                    // tv fully consumed by K1
    mask = (unsigned char*)((float*)d_in[0] + D);
  }

  const int gA = (int)(D / 8192);  // 512
  const int gB = 8192 / 16;        // 512

  // K1: combined = sum_t w_t*tv_t, *B, FWHT1-low  -> bufA
  passA<0><<<gA, 512, 0, stream>>>(tv, bufA, B, nullptr, w, D);
  hipMemsetAsync(mask, 0, (size_t)D, stream);
  scatter_mask<<<(m + 511)/512, 512, 0, stream>>>(rowIx, mask, m);
  // K2: FWHT1-high, *2^-11                         (bufA in-place)
  passB<0><<<gB, 512, 0, stream>>>(bufA, bufA, nullptr, nullptr, nullptr);
  // K3: gather Pi, *G, FWHT2-low                   bufA -> out
  passA<1><<<gA, 512, 0, stream>>>(bufA, out, G, Pi, nullptr, D);
  // K4: FWHT2-high, *2^-11, *mask, FWHT3-high      (out in-place)
  passB<1><<<gB, 512, 0, stream>>>(out, out, mask, nullptr, nullptr);
  // K5: FWHT3-low, *2^-11, *G                      (out in-place)
  passA<2><<<gA, 512, 0, stream>>>(out, out, G, nullptr, nullptr, D);
  // K6: gather inv_Pi, FWHT4-low                   out -> bufA
  passA<3><<<gA, 512, 0, stream>>>(out, bufA, nullptr, invPi, nullptr, D);
  // K7: FWHT4-high, *2^-11*B + pretrained          bufA -> out
  passB<2><<<gB, 512, 0, stream>>>(bufA, out, nullptr, B, prew);
}